// Round 8
// baseline (360.221 us; speedup 1.0000x reference)
//
#include <hip/hip_runtime.h>
#include <cstdint>

#define D 128
#define NPTS 200000
#define KNN 50
#define CAP 8192
#define NS 8192
#define SLACK 2.0f
#define BAND 4.0f
#define EB 2048

// ---- workspace byte offsets ----
#define OFF_ACC    0         // 32 f32 (zeroed in-kernel)
#define OFF_SEL    256       // 16 u32 (zeroed in-kernel; sel[15] = rp done-counter)
#define OFF_CNT    1024      // 256*16 u32 (zeroed in-kernel, 1 counter / 64B line)
#define OFF_HIST0  17408     // 4096*8 u32 sharded (zeroed in-kernel)
#define OFF_HIST12 148480    // 2*2*4096 u32 (zeroed in-kernel)
#define ZERO_BYTES 214016    // zeroed by phase1 blocks 12760..12763
#define OFF_COMB   214016    // 512*128 f32
#define OFF_D2     476160    // 262144 f32
#define OFF_XN     1524736   // 200000 f32
#define OFF_SAMP   2324736   // 256*8192 f32
#define OFF_EBUF   2324736   // alias: 1024*2048 u32 candidate lists (samp dead after h1thr)
#define OFF_THR    10713344  // 256 f32
#define OFF_CANDI  10714368  // 256*8192 i32
#define OFF_SCO    19102976  // 1024*2048 u32 block-local approx-score-key lists
#define OFF_TQSW   27491584  // 256*128 bf16 swizzled
#define OFF_XBF    27557120  // 200000*128 bf16 swizzled (51.2 MB)
#define OFF_ANCP   78757120  // 256 f32 anchor partials (every slot written -> no zeroing)
#define OFF_WREGP  78758144  // 4 f32 W-reg partials (every slot written -> no zeroing)
#define OFF_BCNT   78758400  // 1024 u32 block counts (every filter block writes -> no zeroing)
#define OFF_KSA    78774272  // 256*8192 u32 scattered approx keys

typedef __attribute__((ext_vector_type(8))) short bf16x8;
typedef __attribute__((ext_vector_type(4))) float f32x4;
typedef const __attribute__((address_space(1))) void* gas_p;
typedef __attribute__((address_space(3))) void* las_p;

__device__ __forceinline__ unsigned fkey(float f) {
    unsigned u = __float_as_uint(f);
    return u ^ ((unsigned)((int)u >> 31) | 0x80000000u);
}

// async-stage 8KB chunk (4096 ushorts) into LDS: wave-uniform lds base, lane*16B implicit
__device__ __forceinline__ void stage8k(const unsigned short* __restrict__ g,
                                        unsigned short* l, int w, int lane)
{
    #pragma unroll
    for (int j = 0; j < 2; j++) {
        const unsigned short* gp = g + j * 2048 + w * 512 + lane * 8;
        unsigned short* lp = l + j * 2048 + w * 512;
        __builtin_amdgcn_global_load_lds((gas_p)gp, (las_p)lp, 16, 0, 0);
    }
}

// ---- phase 1: X->bf16 swizzle + xnorm | Tq=qW^T+b (+swizzle, anchor partials) | comb X[idx]
//      | W-reg partials | workspace zeroing (blocks 12760..12763) ----
__global__ void k_phase1(const float* __restrict__ q, const float* __restrict__ X,
                         const float* __restrict__ W, const float* __restrict__ bb,
                         const int* __restrict__ idx, float* __restrict__ comb,
                         unsigned short* __restrict__ tqsw, unsigned short* __restrict__ xbf,
                         float* __restrict__ xn, float* __restrict__ ancp,
                         float* __restrict__ wregp, float* __restrict__ wszero)
{
    const int blk = blockIdx.x, t = threadIdx.x;
    if (blk < 12500) {
        __shared__ float xr4[4][16];
        const int lr = t & 15;
        const float4* src = (const float4*)(X + ((long)(blk * 16 + lr)) * D + (t >> 4) * 8);
        float4 v0 = src[0], v1 = src[1];
        uint4 pk;
        pk.x = (__float_as_uint(v0.x) >> 16) | (__float_as_uint(v0.y) & 0xFFFF0000u);
        pk.y = (__float_as_uint(v0.z) >> 16) | (__float_as_uint(v0.w) & 0xFFFF0000u);
        pk.z = (__float_as_uint(v1.x) >> 16) | (__float_as_uint(v1.y) & 0xFFFF0000u);
        pk.w = (__float_as_uint(v1.z) >> 16) | (__float_as_uint(v1.w) & 0xFFFF0000u);
        *(uint4*)(xbf + (long)blk * 2048 + t * 8) = pk;
        float ssq = v0.x*v0.x + v0.y*v0.y + v0.z*v0.z + v0.w*v0.w
                  + v1.x*v1.x + v1.y*v1.y + v1.z*v1.z + v1.w*v1.w;
        // wave reduce: lanes (i, i+16, i+32, i+48) share the same row lr
        ssq += __shfl_down(ssq, 32);
        ssq += __shfl_down(ssq, 16);
        if ((t & 63) < 16) xr4[t >> 6][lr] = ssq;
        __syncthreads();
        if (t < 16) xn[blk * 16 + t] = xr4[0][t] + xr4[1][t] + xr4[2][t] + xr4[3][t];
    } else if (blk < 12628) {
        __shared__ float rowv[2][D];
        __shared__ float red[2][D];
        const int half = t >> 7, tt = t & 127;
        const int row = (blk - 12500) * 2 + half;
        rowv[half][tt] = q[row * D + tt];
        __syncthreads();
        float s = 0.f;
        const float* wr = W + tt * D;
        #pragma unroll 4
        for (int k = 0; k < D; k++) s = fmaf(rowv[half][k], wr[k], s);
        s += bb[tt];
        comb[row * D + tt] = s;
        unsigned ub = __float_as_uint(s);
        unsigned short hv = (unsigned short)((ub + 0x7fffu + ((ub >> 16) & 1u)) >> 16);
        int ksb = tt >> 5, quad = (tt & 31) >> 3, jj = tt & 7;
        int lane = quad * 16 + (row & 15);
        tqsw[(row >> 4) * 2048 + ksb * 512 + lane * 8 + jj] = hv;
        float dd = s - rowv[half][tt];
        red[half][tt] = dd * dd;
        __syncthreads();
        for (int off = 64; off > 0; off >>= 1) { if (tt < off) red[half][tt] += red[half][tt + off]; __syncthreads(); }
        if (tt == 0) ancp[row] = red[half][0];
    } else if (blk < 12756) {
        const int half = t >> 7, tt = t & 127;
        const int i = (blk - 12628) * 2 + half;
        comb[(256 + i) * D + tt] = X[(long)idx[i] * D + tt];
    } else if (blk < 12760) {
        __shared__ float wred[4];
        const int base = (blk - 12756) * 4096;
        float s = 0.f;
        #pragma unroll 4
        for (int k = 0; k < 16; k++) { float v = W[base + k * 256 + t]; s = fmaf(v, v, s); }
        if (blk == 12756 && t < D) { float v = bb[t]; s = fmaf(v, v, s); }
        #pragma unroll
        for (int off = 32; off > 0; off >>= 1) s += __shfl_down(s, off);
        if ((t & 63) == 0) wred[t >> 6] = s;
        __syncthreads();
        if (t == 0) wregp[blk - 12756] = wred[0] + wred[1] + wred[2] + wred[3];
    } else {
        // zero the accumulator/hist region (acc, sel, cnt, hist0, hist12) - 214016 B
        uint4* z = (uint4*)wszero;
        const uint4 zz = make_uint4(0u, 0u, 0u, 0u);
        for (int i = (blk - 12760) * 256 + t; i < (ZERO_BYTES / 16); i += 1024) z[i] = zz;
    }
}

// ---- merged: D2 (512x512) + fused 12-bit histogram (blocks 0..1023) | mf0 samples matmul (1024..1279) ----
__global__ void k_d2m(const float* __restrict__ comb, float* __restrict__ D2w,
                      unsigned* __restrict__ hist0, const unsigned short* __restrict__ tqsw,
                      const unsigned short* __restrict__ xbf, const float* __restrict__ xn,
                      float* __restrict__ samp)
{
    __shared__ __align__(16) char smraw[51456];
    const int b = blockIdx.x, t = threadIdx.x;
    if (b < 1024) {
        float (*cj)[D + 1] = (float(*)[D + 1])smraw;          // 64*129*4 = 33024
        float (*ci)[D]     = (float(*)[D])(smraw + 33024);    // 4*128*4 = 2048
        unsigned* h        = (unsigned*)(smraw + 35072);      // 4096*4 = 16384
        const int ib = b >> 3, jb = b & 7;
        const int w = t >> 6, l = t & 63;
        for (int m = t; m < 4096; m += 256) h[m] = 0;
        const int irow = ib * 4 + w;
        ci[w][l] = comb[irow * D + l];
        ci[w][l + 64] = comb[irow * D + l + 64];
        const float4* src = (const float4*)(comb + (jb * 64) * D);
        #pragma unroll
        for (int m = 0; m < 8; m++) {
            int u = m * 256 + t;
            int r = u >> 5, c = u & 31;
            float4 v = src[u];
            cj[r][c * 4 + 0] = v.x; cj[r][c * 4 + 1] = v.y; cj[r][c * 4 + 2] = v.z; cj[r][c * 4 + 3] = v.w;
        }
        __syncthreads();
        float s = 0.f;
        #pragma unroll 4
        for (int k = 0; k < D; k++) { float d = ci[w][k] - cj[l][k]; s = fmaf(d, d, s); }
        D2w[irow * 512 + jb * 64 + l] = s;
        atomicAdd(&h[__float_as_uint(s) >> 20], 1u);
        __syncthreads();
        const int sh = (ib + jb) & 7;
        for (int m = t; m < 4096; m += 256) { unsigned v = h[m]; if (v) atomicAdd(&hist0[m * 8 + sh], v); }
    } else {
        unsigned short* sb = (unsigned short*)smraw; // 8 KB chunk
        const int w = t >> 6, lane = t & 63;
        const int lr = lane & 15, quad = lane >> 4;
        const int ck = b - 1024;
        stage8k(xbf + (long)ck * 4096, sb, w, lane);
        bf16x8 a[4][4];
        #pragma unroll
        for (int i = 0; i < 4; i++)
            #pragma unroll
            for (int ks = 0; ks < 4; ks++)
                a[i][ks] = *(const bf16x8*)(tqsw + (w * 4 + i) * 2048 + ks * 512 + lane * 8);
        __syncthreads();
        #pragma unroll
        for (int tt = 0; tt < 2; tt++) {
            const int r = (ck * 2 + tt) * 16 + lr;
            float xnv = xn[r];
            bf16x8 bfr[4];
            #pragma unroll
            for (int ks = 0; ks < 4; ks++)
                bfr[ks] = *(const bf16x8*)(sb + tt * 2048 + ks * 512 + lane * 8);
            f32x4 acc4[4];
            #pragma unroll
            for (int i = 0; i < 4; i++) acc4[i] = (f32x4){0.f, 0.f, 0.f, 0.f};
            #pragma unroll
            for (int ks = 0; ks < 4; ks++)
                #pragma unroll
                for (int i = 0; i < 4; i++)
                    acc4[i] = __builtin_amdgcn_mfma_f32_16x16x32_bf16(a[i][ks], bfr[ks], acc4[i], 0, 0, 0);
            #pragma unroll
            for (int i = 0; i < 4; i++)
                #pragma unroll
                for (int reg = 0; reg < 4; reg++) {
                    int qq = w * 64 + i * 16 + quad * 4 + reg;
                    samp[qq * NS + r] = xnv - 2.f * acc4[i][reg];
                }
        }
    }
}

// ---- hist pass1 w/ redundant-local scan0 (blocks 0..255) + per-query thr-search in regs (256..511) ----
__global__ void k_h1thr(const float* __restrict__ D2w, unsigned* __restrict__ hist12,
                        const unsigned* __restrict__ hist0, unsigned* __restrict__ sel,
                        const float* __restrict__ samp, float* __restrict__ thr)
{
    __shared__ unsigned buf[8192];
    __shared__ unsigned bins[4096];
    __shared__ unsigned part[256];
    __shared__ unsigned selll[4];
    __shared__ unsigned wred[4];
    const int t = threadIdx.x;
    if (blockIdx.x < 256) {
        // local scan0: per-bin sums from sharded hist0 (identical in every block; no serialization)
        unsigned s = 0;
        #pragma unroll
        for (int m = 0; m < 16; m++) {
            int bin = t * 16 + m;
            unsigned bs = 0;
            #pragma unroll
            for (int sh = 0; sh < 8; sh++) bs += hist0[bin * 8 + sh];
            bins[bin] = bs;
            s += bs;
        }
        part[t] = s;
        for (int m = t; m < 8192; m += 256) buf[m] = 0;
        __syncthreads();
        if (t == 0) {
            for (int tg = 0; tg < 2; tg++) {
                unsigned r = tg ? 131072u : 131071u;
                int c = 0;
                while (part[c] <= r) { r -= part[c]; c++; }
                int b = c * 16;
                while (bins[b] <= r) { r -= bins[b]; b++; }
                selll[2 * tg] = (unsigned)b; selll[2 * tg + 1] = r;
            }
            if (blockIdx.x == 0) {
                sel[0] = selll[0]; sel[1] = selll[1]; sel[2] = selll[2]; sel[3] = selll[3];
            }
        }
        __syncthreads();
        unsigned p0 = selll[0], p1 = selll[2];
        const int e0 = blockIdx.x * 1024;
        for (int m = 0; m < 4; m++) {
            unsigned key = __float_as_uint(D2w[e0 + m * 256 + t]);
            if ((key >> 20) == p0) atomicAdd(&buf[(key >> 8) & 0xFFFu], 1u);
            if ((key >> 20) == p1) atomicAdd(&buf[4096 + ((key >> 8) & 0xFFFu)], 1u);
        }
        __syncthreads();
        for (int m = t; m < 8192; m += 256) { unsigned v = buf[m]; if (v) atomicAdd(&hist12[m], v); }
    } else {
        const int q = blockIdx.x - 256;
        // keys register-resident: 32 per thread, statically indexed
        unsigned kreg[32];
        #pragma unroll
        for (int i = 0; i < 32; i++) kreg[i] = fkey(samp[q * NS + i * 256 + t]);
        unsigned v = 0;
        for (int bit = 31; bit >= 0; bit--) {
            unsigned trial = v | (1u << bit);
            unsigned c = 0;
            #pragma unroll
            for (int i = 0; i < 32; i++) c += (kreg[i] < trial) ? 1u : 0u;
            #pragma unroll
            for (int off = 32; off > 0; off >>= 1) c += __shfl_down(c, off);
            if ((t & 63) == 0) wred[t >> 6] = c;
            __syncthreads();
            unsigned total = wred[0] + wred[1] + wred[2] + wred[3];
            __syncthreads();
            if (total <= (unsigned)(KNN - 1)) v = trial;
        }
        if (t == 0) {
            unsigned orig = (v & 0x80000000u) ? (v ^ 0x80000000u) : ~v;
            thr[q] = __uint_as_float(orig) + SLACK;
        }
    }
}

// filter tile body over a statically-named LDS buffer (keeps alias analysis exact so
// prefetch into the OTHER buffer overlaps with these ds_reads); also records approx score key
#define FILT_BODY(SBUF)                                                              \
    do {                                                                             \
        _Pragma("unroll")                                                            \
        for (int tt = 0; tt < 2; tt++) {                                             \
            const int r = (ck * 2 + tt) * 16 + lr;                                   \
            float xnv = xn[r];                                                       \
            bf16x8 bv[4];                                                            \
            _Pragma("unroll")                                                        \
            for (int ks2 = 0; ks2 < 4; ks2++)                                        \
                bv[ks2] = *(const bf16x8*)(SBUF + tt * 2048 + ks2 * 512 + lane * 8); \
            f32x4 acc4[4];                                                           \
            _Pragma("unroll")                                                        \
            for (int i = 0; i < 4; i++) acc4[i] = (f32x4){0.f, 0.f, 0.f, 0.f};       \
            _Pragma("unroll")                                                        \
            for (int ks2 = 0; ks2 < 4; ks2++)                                        \
                _Pragma("unroll")                                                    \
                for (int i = 0; i < 4; i++)                                          \
                    acc4[i] = __builtin_amdgcn_mfma_f32_16x16x32_bf16(a[i][ks2], bv[ks2], acc4[i], 0, 0, 0); \
            _Pragma("unroll")                                                        \
            for (int i = 0; i < 4; i++)                                              \
                _Pragma("unroll")                                                    \
                for (int reg = 0; reg < 4; reg++) {                                  \
                    float s = xnv - 2.f * acc4[i][reg];                              \
                    if (s <= th_r[i][reg]) {                                         \
                        unsigned qq = (unsigned)(w * 64 + i * 16 + quad * 4 + reg);  \
                        unsigned p = atomicAdd(&lcnt, 1u);                           \
                        if (p < 1024u) { lbuf[p] = (qq << 18) | (unsigned)r; lsco[p] = fkey(s); } \
                        else {                                                       \
                            unsigned dd2 = gbase + p;                                \
                            if (dd2 < EB) { eb[dd2] = (qq << 18) | (unsigned)r; ebs[dd2] = fkey(s); } \
                        }                                                            \
                    }                                                                \
                }                                                                    \
        }                                                                            \
    } while (0)

// ---- filt2: mf1-filter -> per-block lists (blocks 0..1023) | hist pass2 compact (1024..1279) ----
__global__ __launch_bounds__(256) void k_filt2(const unsigned short* __restrict__ tqsw,
    const unsigned short* __restrict__ xbf, const float* __restrict__ xn,
    const float* __restrict__ thr, unsigned* __restrict__ ebuf, unsigned* __restrict__ esco,
    unsigned* __restrict__ bcnt, const float* __restrict__ D2w,
    unsigned* __restrict__ hist12, unsigned* __restrict__ sel)
{
    if (blockIdx.x >= 1024) {
        // hist pass2 (compact 2KB LDS) + scan1; block 1024 persists sel[4..7]
        __shared__ unsigned h2c[512];
        __shared__ unsigned part2[256];
        __shared__ unsigned pfx[2];
        __shared__ unsigned rr[2];
        const int t = threadIdx.x;
        for (int tg = 0; tg < 2; tg++) {
            const unsigned* hh = hist12 + tg * 4096;
            unsigned s = 0;
            for (int m = 0; m < 16; m++) s += hh[t * 16 + m];
            part2[t] = s;
            __syncthreads();
            if (t == 0) {
                unsigned r = sel[1 + 2 * tg];
                int c = 0;
                while (part2[c] <= r) { r -= part2[c]; c++; }
                int b = c * 16;
                while (hh[b] <= r) { r -= hh[b]; b++; }
                pfx[tg] = (sel[2 * tg] << 12) | (unsigned)b;
                rr[tg] = r;
            }
            __syncthreads();
        }
        if (blockIdx.x == 1024 && t == 0) {
            sel[4] = pfx[0]; sel[5] = rr[0]; sel[6] = pfx[1]; sel[7] = rr[1];
        }
        h2c[t] = 0; h2c[256 + t] = 0;
        __syncthreads();
        unsigned p0 = pfx[0], p1 = pfx[1];
        const int e0 = (blockIdx.x - 1024) * 1024;
        for (int m = 0; m < 4; m++) {
            unsigned key = __float_as_uint(D2w[e0 + m * 256 + t]);
            if ((key >> 8) == p0) atomicAdd(&h2c[key & 0xFFu], 1u);
            if ((key >> 8) == p1) atomicAdd(&h2c[256 + (key & 0xFFu)], 1u);
        }
        __syncthreads();
        unsigned* gp = hist12 + 8192;
        unsigned v0 = h2c[t], v1 = h2c[256 + t];
        if (v0) atomicAdd(&gp[t], v0);
        if (v1) atomicAdd(&gp[4096 + t], v1);
        return;
    }
    __shared__ unsigned short sbA[4096]; // statically-named double buffers (alias-exact)
    __shared__ unsigned short sbB[4096];
    __shared__ unsigned lbuf[1024];      // packed (qq<<18)|r candidates
    __shared__ unsigned lsco[1024];      // matching approx score keys
    __shared__ unsigned lcnt;
    __shared__ unsigned gbase;           // running write offset into this block's ebuf list
    const int t = threadIdx.x;
    const int w = t >> 6, lane = t & 63;
    const int lr = lane & 15, quad = lane >> 4;
    unsigned* eb  = ebuf + (unsigned)blockIdx.x * EB;
    unsigned* ebs = esco + (unsigned)blockIdx.x * EB;
    bf16x8 a[4][4];
    #pragma unroll
    for (int i = 0; i < 4; i++)
        #pragma unroll
        for (int ks = 0; ks < 4; ks++)
            a[i][ks] = *(const bf16x8*)(tqsw + (w * 4 + i) * 2048 + ks * 512 + lane * 8);
    float th_r[4][4];
    #pragma unroll
    for (int i = 0; i < 4; i++)
        #pragma unroll
        for (int reg = 0; reg < 4; reg++)
            th_r[i][reg] = thr[w * 64 + i * 16 + quad * 4 + reg];
    int ck = blockIdx.x;
    bool phaseA = true;
    if (t == 0) { lcnt = 0; gbase = 0; }
    stage8k(xbf + (long)ck * 4096, sbA, w, lane);
    __syncthreads();
    while (true) {
        const int ckn = ck + 1024;
        const bool has = ckn < 6250;
        if (phaseA) {
            if (has) stage8k(xbf + (long)ckn * 4096, sbB, w, lane);
            FILT_BODY(sbA);
        } else {
            if (has) stage8k(xbf + (long)ckn * 4096, sbA, w, lane);
            FILT_BODY(sbB);
        }
        __syncthreads(); // publishes lcnt/lbuf; drains prefetch into the other buffer
        unsigned n = lcnt;
        if (!has || n >= 512u) {
            unsigned nf = (n < 1024u) ? n : 1024u;
            unsigned gb = gbase;
            for (unsigned m = t; m < nf; m += 256) {
                unsigned d = gb + m;
                if (d < EB) { eb[d] = lbuf[m]; ebs[d] = lsco[m]; }
            }
            __syncthreads();
            if (t == 0) { gbase = gb + n; lcnt = 0; }
            __syncthreads();
        }
        if (!has) break;
        ck = ckn; phaseA = !phaseA;
    }
    if (t == 0) bcnt[blockIdx.x] = (gbase < EB) ? gbase : EB;
}

// ---- scatmmd: scatter lists (idx + approx key) -> per-query arrays (0..127) | mmd exp-sum (128..383) ----
__global__ __launch_bounds__(256) void k_scatmmd(const unsigned* __restrict__ ebuf,
    const unsigned* __restrict__ esco, const unsigned* __restrict__ bcnt,
    int* __restrict__ cand_i, unsigned* __restrict__ ksa, unsigned* __restrict__ cnt,
    const float* __restrict__ D2w, const unsigned* __restrict__ hist12,
    const unsigned* __restrict__ sel, float* __restrict__ acc)
{
    const int t = threadIdx.x;
    if (blockIdx.x >= 128) {
        __shared__ unsigned h2[512];
        __shared__ float gsh;
        __shared__ float part[12];
        const int w = t >> 6;
        h2[t] = hist12[8192 + t];
        h2[256 + t] = hist12[8192 + 4096 + t];
        __syncthreads();
        if (t == 0) {
            unsigned key[2];
            for (int tg = 0; tg < 2; tg++) {
                unsigned r = sel[5 + 2 * tg];
                const unsigned* hh = h2 + tg * 256;
                int b = 0;
                while (hh[b] <= r) { r -= hh[b]; b++; }
                key[tg] = (sel[4 + 2 * tg] << 8) | (unsigned)b;
            }
            float med = 0.5f * (__uint_as_float(key[0]) + __uint_as_float(key[1]));
            float ssq = 0.5f * med;
            if (ssq < 1e-6f) ssq = 1.0f;
            gsh = 1.0f / (ssq + 1e-8f);
        }
        __syncthreads();
        const float g = gsh;
        float s[3] = {0.f, 0.f, 0.f};
        const int e0 = (blockIdx.x - 128) * 1024;
        #pragma unroll
        for (int m = 0; m < 4; m++) {
            int e = e0 + m * 256 + t;
            int i = e >> 9, j = e & 511;
            float v = expf(-g * D2w[e]);
            int qd = (i < 256) ? ((j < 256) ? 0 : 2) : ((j < 256) ? 2 : 1);
            s[qd] += v;
        }
        #pragma unroll
        for (int c = 0; c < 3; c++) {
            float x = s[c];
            #pragma unroll
            for (int off = 32; off > 0; off >>= 1) x += __shfl_down(x, off);
            if ((t & 63) == 0) part[w * 3 + c] = x;
        }
        __syncthreads();
        if (t == 0)
            for (int c = 0; c < 3; c++)
                atomicAdd(&acc[2 + c], part[c] + part[3 + c] + part[6 + c] + part[9 + c]);
        return;
    }
    __shared__ unsigned hist[256];
    __shared__ unsigned startp[256];
    const int b0 = blockIdx.x * 8;   // 128 blocks x 8 lists = 1024 lists
    hist[t] = 0;
    __syncthreads();
    for (int b = b0; b < b0 + 8; b++) {
        unsigned n = bcnt[b];
        const unsigned* e = ebuf + (unsigned)b * EB;
        for (unsigned m = t; m < n; m += 256)
            atomicAdd(&hist[e[m] >> 18], 1u);
    }
    __syncthreads();
    unsigned c = hist[t];
    if (c) {
        unsigned base = atomicAdd(&cnt[t * 16], c);
        startp[t] = ((unsigned)t << 13) + base;
    }
    __syncthreads();
    for (int b = b0; b < b0 + 8; b++) {
        unsigned n = bcnt[b];
        const unsigned* e = ebuf + (unsigned)b * EB;
        const unsigned* e2 = esco + (unsigned)b * EB;
        for (unsigned m = t; m < n; m += 256) {
            unsigned ent = e[m];
            unsigned sk = e2[m];
            unsigned qq = ent >> 18;
            unsigned pos = atomicAdd(&startp[qq], 1u);
            if (pos < ((qq + 1u) << 13)) { cand_i[pos] = (int)(ent & 0x3FFFFu); ksa[pos] = sk; }
        }
    }
}

// ---- rp: approx-band prune -> exact rescore of survivors -> top-50 -> softmax -> union KL;
//      last block assembles the final output ----
__global__ __launch_bounds__(1024) void k_rp(const float* __restrict__ comb,
                        const float* __restrict__ X,
                        const int* __restrict__ cand_i, const unsigned* __restrict__ ksa,
                        const unsigned* __restrict__ cnt,
                        const int* __restrict__ pri,
                        const float* __restrict__ prw, const int* __restrict__ qix,
                        const float* __restrict__ xn,
                        float* __restrict__ acc, unsigned* __restrict__ sel,
                        const float* __restrict__ ancp, const float* __restrict__ wregp,
                        float* __restrict__ out)
{
    __shared__ unsigned ks[CAP];     // approx keys (full path: overwritten by exact keys)
    __shared__ int sidx[2048];       // survivor candidate indices (compact path)
    __shared__ unsigned eks[2048];   // survivor exact keys (compact path)
    __shared__ float qrow[D];
    __shared__ unsigned wred[16];
    __shared__ unsigned scnt, wpos, eqn;
    __shared__ int eq[64];
    __shared__ int pidx[KNN];
    __shared__ float l2s[KNN];
    __shared__ float pw[KNN];
    __shared__ int ci[100];
    __shared__ float pwv[50], qwv[50];
    __shared__ float pterm[100], qterm[100], kterm[100];
    __shared__ float Sp, Sq;
    const int q = blockIdx.x, t = threadIdx.x;
    if (t < D) qrow[t] = comb[q * D + t];
    if (t == 0) { wpos = 0; eqn = 0; scnt = 0; }
    unsigned nn = cnt[q * 16];
    const int n = (nn < (unsigned)CAP) ? (int)nn : CAP;
    for (int m = t; m < n; m += 1024) ks[m] = ksa[q * CAP + m];
    __syncthreads();
    // ---- bit-search the approx kth key ----
    unsigned kregA[8];
    #pragma unroll
    for (int i = 0; i < 8; i++) {
        int m = i * 1024 + t;
        kregA[i] = (m < n) ? ks[m] : 0xFFFFFFFFu;
    }
    int kk = KNN - 1; if (kk > n - 1) kk = n - 1;
    unsigned va = 0;
    for (int bit = 31; bit >= 0; bit--) {
        unsigned trial = va | (1u << bit);
        unsigned c = 0;
        #pragma unroll
        for (int i = 0; i < 8; i++) c += (kregA[i] < trial) ? 1u : 0u;
        #pragma unroll
        for (int off = 32; off > 0; off >>= 1) c += __shfl_down(c, off);
        if ((t & 63) == 0) wred[t >> 6] = c;
        __syncthreads();
        unsigned total = 0;
        #pragma unroll
        for (int i = 0; i < 16; i++) total += wred[i];
        __syncthreads();
        if (total <= (unsigned)kk) va = trial;
    }
    // ---- survivor band: approx dist <= approx-50th dist + BAND ----
    unsigned ovaf = (va & 0x80000000u) ? (va ^ 0x80000000u) : ~va;
    unsigned vkeep = fkey(__uint_as_float(ovaf) + BAND);
    for (int m = t; m < n; m += 1024) {
        if (ks[m] <= vkeep) {
            unsigned p = atomicAdd(&scnt, 1u);
            if (p < 2048u) sidx[p] = cand_i[q * CAP + m];
        }
    }
    __syncthreads();
    const bool cpath = (scnt <= 2048u);       // block-uniform
    const int ns = cpath ? (int)scnt : n;
    // ---- exact f32 rescore (survivors only, or all on overflow fallback) ----
    const int g = t >> 3, j = t & 7;          // 128 groups of 8 lanes
    if (cpath) {
        for (int m = g; m < ns; m += 128) {
            int r = sidx[m];
            const float4* xr = (const float4*)(X + (long)r * D);
            float s = 0.f;
            #pragma unroll
            for (int p = 0; p < 4; p++) {
                float4 xv = xr[j * 4 + p];
                float4 qv = *(const float4*)&qrow[(j * 4 + p) * 4];
                s = fmaf(xv.x, qv.x, fmaf(xv.y, qv.y, fmaf(xv.z, qv.z, fmaf(xv.w, qv.w, s))));
            }
            s += __shfl_down(s, 4); s += __shfl_down(s, 2); s += __shfl_down(s, 1);
            if (j == 0) eks[m] = fkey(xn[r] - 2.f * s);
        }
    } else {
        for (int m = g; m < ns; m += 128) {
            int r = cand_i[q * CAP + m];
            const float4* xr = (const float4*)(X + (long)r * D);
            float s = 0.f;
            #pragma unroll
            for (int p = 0; p < 4; p++) {
                float4 xv = xr[j * 4 + p];
                float4 qv = *(const float4*)&qrow[(j * 4 + p) * 4];
                s = fmaf(xv.x, qv.x, fmaf(xv.y, qv.y, fmaf(xv.z, qv.z, fmaf(xv.w, qv.w, s))));
            }
            s += __shfl_down(s, 4); s += __shfl_down(s, 2); s += __shfl_down(s, 1);
            if (j == 0) ks[m] = fkey(xn[r] - 2.f * s);   // overwrite approx keys
        }
    }
    __syncthreads();
    // ---- exact kth among ns keys ----
    kk = KNN - 1; if (kk > ns - 1) kk = ns - 1;
    unsigned v = 0;
    for (int bit = 31; bit >= 0; bit--) {
        unsigned trial = v | (1u << bit);
        unsigned c = 0;
        for (int m = t; m < ns; m += 1024) {
            unsigned kv = cpath ? eks[m] : ks[m];
            c += (kv < trial) ? 1u : 0u;
        }
        #pragma unroll
        for (int off = 32; off > 0; off >>= 1) c += __shfl_down(c, off);
        if ((t & 63) == 0) wred[t >> 6] = c;
        __syncthreads();
        unsigned total = 0;
        #pragma unroll
        for (int i = 0; i < 16; i++) total += wred[i];
        __syncthreads();
        if (total <= (unsigned)kk) v = trial;
    }
    for (int m = t; m < ns; m += 1024) {
        unsigned kv = cpath ? eks[m] : ks[m];
        int r = cpath ? sidx[m] : cand_i[q * CAP + m];
        if (kv < v) {
            unsigned p = atomicAdd(&wpos, 1u);
            pidx[p] = r;
        } else if (kv == v) {
            unsigned p = atomicAdd(&eqn, 1u);
            if (p < 64) eq[p] = r;
        }
    }
    __syncthreads();
    if (t == 0) {
        int c1 = (int)wpos, need = KNN - c1;
        int ne = (eqn < 64u) ? (int)eqn : 64;
        for (int a = 0; a < ne; a++)
            for (int b2 = a + 1; b2 < ne; b2++)
                if (eq[b2] < eq[a]) { int tmp = eq[a]; eq[a] = eq[b2]; eq[b2] = tmp; }
        for (int a = 0; a < need && a < ne; a++) pidx[c1 + a] = eq[a];
    }
    __syncthreads();
    for (int nb = g; nb < KNN; nb += 128) {
        long r = pidx[nb];
        const float4* xr = (const float4*)(X + r * D);
        float s = 0.f;
        #pragma unroll
        for (int p = 0; p < 4; p++) {
            float4 xv = xr[j * 4 + p];
            float4 qv = *(const float4*)&qrow[(j * 4 + p) * 4];
            float d0 = qv.x - xv.x, d1 = qv.y - xv.y, d2 = qv.z - xv.z, d3 = qv.w - xv.w;
            s += d0 * d0 + d1 * d1 + d2 * d2 + d3 * d3;
        }
        s += __shfl_down(s, 4); s += __shfl_down(s, 2); s += __shfl_down(s, 1);
        if (j == 0) l2s[nb] = s;
    }
    int qi = qix[q];
    if (t >= 128 && t < 178) { int k = t - 128; ci[k] = pri[qi * 50 + k]; pwv[k] = prw[qi * 50 + k]; }
    __syncthreads();
    if (t < 64) {
        float logit = (t < KNN) ? (-l2s[t] * 10.0f) : -3.4e38f; // 1/tau = 10
        float m = logit;
        #pragma unroll
        for (int off = 32; off > 0; off >>= 1) m = fmaxf(m, __shfl_down(m, off));
        m = __shfl(m, 0);
        float e = (t < KNN) ? expf(logit - m) : 0.f;
        float ss = e;
        #pragma unroll
        for (int off = 32; off > 0; off >>= 1) ss += __shfl_down(ss, off);
        ss = __shfl(ss, 0);
        if (t < KNN) pw[t] = e / ss;
    }
    __syncthreads();
    if (t < 50) { ci[50 + t] = pidx[t]; qwv[t] = pw[t]; }
    __syncthreads();
    float pc = 0.f, qc = 0.f, mult = 0.f;
    if (t < 100) {
        int c = ci[t];
        float pr = 0.f, qr = 0.f;
        for (int k = 0; k < 50; k++) {
            bool m1 = (c == ci[k]); bool m2 = (c == ci[50 + k]);
            mult += (m1 ? 1.f : 0.f) + (m2 ? 1.f : 0.f);
            pr += m1 ? pwv[k] : 0.f;
            qr += m2 ? qwv[k] : 0.f;
        }
        pc = fmaxf(pr, 1e-8f); qc = fmaxf(qr, 1e-8f);
        pterm[t] = pc / mult; qterm[t] = qc / mult;
    }
    __syncthreads();
    if (t == 0) { float a = 0.f, b2 = 0.f; for (int m = 0; m < 100; m++) { a += pterm[m]; b2 += qterm[m]; } Sp = a; Sq = b2; }
    __syncthreads();
    if (t < 100) {
        float p = pc / Sp, qq2 = qc / Sq;
        kterm[t] = (p * (logf(p) - logf(qq2))) / mult;
    }
    __syncthreads();
    if (t == 0) {
        float s = 0.f;
        for (int m = 0; m < 100; m++) s += kterm[m];
        atomicAdd(&acc[1], s);
        __threadfence();                              // release this block's contribution
        unsigned old = atomicAdd(&sel[15], 1u);       // device-scope arrival counter
        if (old == 255u) {                            // last block assembles the output
            __threadfence();                          // acquire all blocks' contributions
            float lknn = atomicAdd(&acc[1], 0.f) / 256.f;
            float reg = 0.f;
            #pragma unroll
            for (int m = 0; m < 4; m++) reg += wregp[m];
            reg *= 0.5f;
            float anc = 0.f;
            for (int m = 0; m < 256; m++) anc += ancp[m];
            float lanc = anc / 256.f;
            float kxx = acc[2] / 65536.f, kyy = acc[3] / 65536.f, kxy = acc[4] / 131072.f;
            float ld = fmaxf(kxx + kyy - 2.f * kxy, 0.f);
            out[0] = ld + lknn + 1e-4f * reg + lanc;
            out[1] = ld; out[2] = lknn; out[3] = lanc;
        }
    }
}

extern "C" void kernel_launch(void* const* d_in, const int* in_sizes, int n_in,
                              void* d_out, int out_size, void* d_ws, size_t ws_size,
                              hipStream_t stream)
{
    (void)in_sizes; (void)n_in; (void)out_size; (void)ws_size;
    const float* q   = (const float*)d_in[0];
    const float* X   = (const float*)d_in[1];
    const float* W   = (const float*)d_in[2];
    const float* bb  = (const float*)d_in[3];
    const float* prw = (const float*)d_in[4];
    const int*   pri = (const int*)d_in[5];
    const int*   qix = (const int*)d_in[6];
    const int*   idx = (const int*)d_in[7];
    float* out = (float*)d_out;
    char* ws = (char*)d_ws;
    float*    acc   = (float*)(ws + OFF_ACC);
    unsigned* sel   = (unsigned*)(ws + OFF_SEL);
    unsigned* cnt   = (unsigned*)(ws + OFF_CNT);
    unsigned* hist0 = (unsigned*)(ws + OFF_HIST0);
    unsigned* hist12= (unsigned*)(ws + OFF_HIST12);
    float*    comb  = (float*)(ws + OFF_COMB);
    float*    D2w   = (float*)(ws + OFF_D2);
    float*    xn    = (float*)(ws + OFF_XN);
    float*    samp  = (float*)(ws + OFF_SAMP);
    float*    thr   = (float*)(ws + OFF_THR);
    int*      cix   = (int*)(ws + OFF_CANDI);
    unsigned* ebuf  = (unsigned*)(ws + OFF_EBUF);   // aliases samp (dead after k_h1thr)
    unsigned* esco  = (unsigned*)(ws + OFF_SCO);
    unsigned* bcnt  = (unsigned*)(ws + OFF_BCNT);
    unsigned* ksa   = (unsigned*)(ws + OFF_KSA);
    unsigned short* tqsw = (unsigned short*)(ws + OFF_TQSW);
    unsigned short* xbf  = (unsigned short*)(ws + OFF_XBF);
    float*    ancp  = (float*)(ws + OFF_ANCP);
    float*    wregp = (float*)(ws + OFF_WREGP);

    hipLaunchKernelGGL(k_phase1,  dim3(12764),   dim3(256), 0, stream, q, X, W, bb, idx, comb, tqsw, xbf, xn, ancp, wregp, acc);
    hipLaunchKernelGGL(k_d2m,     dim3(1280),    dim3(256), 0, stream, comb, D2w, hist0, tqsw, xbf, xn, samp);
    hipLaunchKernelGGL(k_h1thr,   dim3(512),     dim3(256), 0, stream, D2w, hist12, hist0, sel, samp, thr);
    hipLaunchKernelGGL(k_filt2,   dim3(1280),    dim3(256), 0, stream, tqsw, xbf, xn, thr, ebuf, esco, bcnt, D2w, hist12, sel);
    hipLaunchKernelGGL(k_scatmmd, dim3(384),     dim3(256), 0, stream, ebuf, esco, bcnt, cix, ksa, cnt, D2w, hist12, sel, acc);
    hipLaunchKernelGGL(k_rp,      dim3(256),     dim3(1024), 0, stream, comb, X, cix, ksa, cnt, pri, prw, qix, xn, acc, sel, ancp, wregp, out);
}

// Round 10
// 336.714 us; speedup vs baseline: 1.0698x; 1.0698x over previous
//
#include <hip/hip_runtime.h>
#include <cstdint>

#define D 128
#define NPTS 200000
#define KNN 50
#define CAP 8192
#define NS 8192
#define SLACK 2.0f
#define BAND 4.0f
#define EB 2048

// ---- workspace byte offsets ----
#define OFF_ACC    0         // 32 f32 (zeroed in-kernel)
#define OFF_SEL    256       // 16 u32 (zeroed in-kernel; sel[15] = rp done-counter)
#define OFF_CNT    1024      // 256*16 u32 (zeroed in-kernel, 1 counter / 64B line)
#define OFF_HIST0  17408     // 4096*8 u32 sharded (zeroed in-kernel)
#define OFF_HIST12 148480    // 2*2*4096 u32 (zeroed in-kernel)
#define ZERO_BYTES 214016    // zeroed by phase1 blocks 12760..12763
#define OFF_COMB   214016    // 512*128 f32
#define OFF_D2     476160    // 262144 f32
#define OFF_XN     1524736   // 200000 f32
#define OFF_SAMP   2324736   // 256*8192 f32
#define OFF_EBUF   2324736   // alias: 1024*2048 u32 candidate lists (samp dead after h1thr)
#define OFF_THR    10713344  // 256 f32
#define OFF_CANDI  10714368  // 256*8192 i32
#define OFF_SCO    19102976  // 1024*2048 u32 block-local approx-score-key lists
#define OFF_TQSW   27491584  // 256*128 bf16 swizzled
#define OFF_XBF    27557120  // 200000*128 bf16 swizzled (51.2 MB)
#define OFF_ANCP   78757120  // 256 f32 anchor partials (every slot written -> no zeroing)
#define OFF_WREGP  78758144  // 4 f32 W-reg partials (every slot written -> no zeroing)
#define OFF_BCNT   78758400  // 1024 u32 block counts (every filter block writes -> no zeroing)
#define OFF_KSA    78774272  // 256*8192 u32 scattered approx keys

typedef __attribute__((ext_vector_type(8))) short bf16x8;
typedef __attribute__((ext_vector_type(4))) float f32x4;
typedef const __attribute__((address_space(1))) void* gas_p;
typedef __attribute__((address_space(3))) void* las_p;

__device__ __forceinline__ unsigned fkey(float f) {
    unsigned u = __float_as_uint(f);
    return u ^ ((unsigned)((int)u >> 31) | 0x80000000u);
}

// async-stage 8KB chunk (4096 ushorts) into LDS: wave-uniform lds base, lane*16B implicit
__device__ __forceinline__ void stage8k(const unsigned short* __restrict__ g,
                                        unsigned short* l, int w, int lane)
{
    #pragma unroll
    for (int j = 0; j < 2; j++) {
        const unsigned short* gp = g + j * 2048 + w * 512 + lane * 8;
        unsigned short* lp = l + j * 2048 + w * 512;
        __builtin_amdgcn_global_load_lds((gas_p)gp, (las_p)lp, 16, 0, 0);
    }
}

// ---- phase 1: X->bf16 swizzle + xnorm | Tq=qW^T+b (+swizzle, anchor partials) | comb X[idx]
//      | W-reg partials | workspace zeroing (blocks 12760..12763) ----
__global__ void k_phase1(const float* __restrict__ q, const float* __restrict__ X,
                         const float* __restrict__ W, const float* __restrict__ bb,
                         const int* __restrict__ idx, float* __restrict__ comb,
                         unsigned short* __restrict__ tqsw, unsigned short* __restrict__ xbf,
                         float* __restrict__ xn, float* __restrict__ ancp,
                         float* __restrict__ wregp, float* __restrict__ wszero)
{
    const int blk = blockIdx.x, t = threadIdx.x;
    if (blk < 12500) {
        __shared__ float xr4[4][16];
        const int lr = t & 15;
        const float4* src = (const float4*)(X + ((long)(blk * 16 + lr)) * D + (t >> 4) * 8);
        float4 v0 = src[0], v1 = src[1];
        uint4 pk;
        pk.x = (__float_as_uint(v0.x) >> 16) | (__float_as_uint(v0.y) & 0xFFFF0000u);
        pk.y = (__float_as_uint(v0.z) >> 16) | (__float_as_uint(v0.w) & 0xFFFF0000u);
        pk.z = (__float_as_uint(v1.x) >> 16) | (__float_as_uint(v1.y) & 0xFFFF0000u);
        pk.w = (__float_as_uint(v1.z) >> 16) | (__float_as_uint(v1.w) & 0xFFFF0000u);
        *(uint4*)(xbf + (long)blk * 2048 + t * 8) = pk;
        float ssq = v0.x*v0.x + v0.y*v0.y + v0.z*v0.z + v0.w*v0.w
                  + v1.x*v1.x + v1.y*v1.y + v1.z*v1.z + v1.w*v1.w;
        // wave reduce: lanes (i, i+16, i+32, i+48) share the same row lr
        ssq += __shfl_down(ssq, 32);
        ssq += __shfl_down(ssq, 16);
        if ((t & 63) < 16) xr4[t >> 6][lr] = ssq;
        __syncthreads();
        if (t < 16) xn[blk * 16 + t] = xr4[0][t] + xr4[1][t] + xr4[2][t] + xr4[3][t];
    } else if (blk < 12628) {
        __shared__ float rowv[2][D];
        __shared__ float red[2][D];
        const int half = t >> 7, tt = t & 127;
        const int row = (blk - 12500) * 2 + half;
        rowv[half][tt] = q[row * D + tt];
        __syncthreads();
        float s = 0.f;
        const float* wr = W + tt * D;
        #pragma unroll 4
        for (int k = 0; k < D; k++) s = fmaf(rowv[half][k], wr[k], s);
        s += bb[tt];
        comb[row * D + tt] = s;
        unsigned ub = __float_as_uint(s);
        unsigned short hv = (unsigned short)((ub + 0x7fffu + ((ub >> 16) & 1u)) >> 16);
        int ksb = tt >> 5, quad = (tt & 31) >> 3, jj = tt & 7;
        int lane = quad * 16 + (row & 15);
        tqsw[(row >> 4) * 2048 + ksb * 512 + lane * 8 + jj] = hv;
        float dd = s - rowv[half][tt];
        red[half][tt] = dd * dd;
        __syncthreads();
        for (int off = 64; off > 0; off >>= 1) { if (tt < off) red[half][tt] += red[half][tt + off]; __syncthreads(); }
        if (tt == 0) ancp[row] = red[half][0];
    } else if (blk < 12756) {
        const int half = t >> 7, tt = t & 127;
        const int i = (blk - 12628) * 2 + half;
        comb[(256 + i) * D + tt] = X[(long)idx[i] * D + tt];
    } else if (blk < 12760) {
        __shared__ float wred[4];
        const int base = (blk - 12756) * 4096;
        float s = 0.f;
        #pragma unroll 4
        for (int k = 0; k < 16; k++) { float v = W[base + k * 256 + t]; s = fmaf(v, v, s); }
        if (blk == 12756 && t < D) { float v = bb[t]; s = fmaf(v, v, s); }
        #pragma unroll
        for (int off = 32; off > 0; off >>= 1) s += __shfl_down(s, off);
        if ((t & 63) == 0) wred[t >> 6] = s;
        __syncthreads();
        if (t == 0) wregp[blk - 12756] = wred[0] + wred[1] + wred[2] + wred[3];
    } else {
        // zero the accumulator/hist region (acc, sel, cnt, hist0, hist12) - 214016 B
        uint4* z = (uint4*)wszero;
        const uint4 zz = make_uint4(0u, 0u, 0u, 0u);
        for (int i = (blk - 12760) * 256 + t; i < (ZERO_BYTES / 16); i += 1024) z[i] = zz;
    }
}

// ---- merged: D2 (512x512) + fused 12-bit histogram (blocks 0..1023) | mf0 samples matmul (1024..1279) ----
__global__ void k_d2m(const float* __restrict__ comb, float* __restrict__ D2w,
                      unsigned* __restrict__ hist0, const unsigned short* __restrict__ tqsw,
                      const unsigned short* __restrict__ xbf, const float* __restrict__ xn,
                      float* __restrict__ samp)
{
    __shared__ __align__(16) char smraw[51456];
    const int b = blockIdx.x, t = threadIdx.x;
    if (b < 1024) {
        float (*cj)[D + 1] = (float(*)[D + 1])smraw;          // 64*129*4 = 33024
        float (*ci)[D]     = (float(*)[D])(smraw + 33024);    // 4*128*4 = 2048
        unsigned* h        = (unsigned*)(smraw + 35072);      // 4096*4 = 16384
        const int ib = b >> 3, jb = b & 7;
        const int w = t >> 6, l = t & 63;
        for (int m = t; m < 4096; m += 256) h[m] = 0;
        const int irow = ib * 4 + w;
        ci[w][l] = comb[irow * D + l];
        ci[w][l + 64] = comb[irow * D + l + 64];
        const float4* src = (const float4*)(comb + (jb * 64) * D);
        #pragma unroll
        for (int m = 0; m < 8; m++) {
            int u = m * 256 + t;
            int r = u >> 5, c = u & 31;
            float4 v = src[u];
            cj[r][c * 4 + 0] = v.x; cj[r][c * 4 + 1] = v.y; cj[r][c * 4 + 2] = v.z; cj[r][c * 4 + 3] = v.w;
        }
        __syncthreads();
        float s = 0.f;
        #pragma unroll 4
        for (int k = 0; k < D; k++) { float d = ci[w][k] - cj[l][k]; s = fmaf(d, d, s); }
        D2w[irow * 512 + jb * 64 + l] = s;
        atomicAdd(&h[__float_as_uint(s) >> 20], 1u);
        __syncthreads();
        const int sh = (ib + jb) & 7;
        for (int m = t; m < 4096; m += 256) { unsigned v = h[m]; if (v) atomicAdd(&hist0[m * 8 + sh], v); }
    } else {
        unsigned short* sb = (unsigned short*)smraw; // 8 KB chunk
        const int w = t >> 6, lane = t & 63;
        const int lr = lane & 15, quad = lane >> 4;
        const int ck = b - 1024;
        stage8k(xbf + (long)ck * 4096, sb, w, lane);
        bf16x8 a[4][4];
        #pragma unroll
        for (int i = 0; i < 4; i++)
            #pragma unroll
            for (int ks = 0; ks < 4; ks++)
                a[i][ks] = *(const bf16x8*)(tqsw + (w * 4 + i) * 2048 + ks * 512 + lane * 8);
        __syncthreads();
        #pragma unroll
        for (int tt = 0; tt < 2; tt++) {
            const int r = (ck * 2 + tt) * 16 + lr;
            float xnv = xn[r];
            bf16x8 bfr[4];
            #pragma unroll
            for (int ks = 0; ks < 4; ks++)
                bfr[ks] = *(const bf16x8*)(sb + tt * 2048 + ks * 512 + lane * 8);
            f32x4 acc4[4];
            #pragma unroll
            for (int i = 0; i < 4; i++) acc4[i] = (f32x4){0.f, 0.f, 0.f, 0.f};
            #pragma unroll
            for (int ks = 0; ks < 4; ks++)
                #pragma unroll
                for (int i = 0; i < 4; i++)
                    acc4[i] = __builtin_amdgcn_mfma_f32_16x16x32_bf16(a[i][ks], bfr[ks], acc4[i], 0, 0, 0);
            #pragma unroll
            for (int i = 0; i < 4; i++)
                #pragma unroll
                for (int reg = 0; reg < 4; reg++) {
                    int qq = w * 64 + i * 16 + quad * 4 + reg;
                    samp[qq * NS + r] = xnv - 2.f * acc4[i][reg];
                }
        }
    }
}

// ---- hist pass1 w/ redundant-local scan0 (blocks 0..255) + per-query thr-search in regs (256..511) ----
__global__ void k_h1thr(const float* __restrict__ D2w, unsigned* __restrict__ hist12,
                        const unsigned* __restrict__ hist0, unsigned* __restrict__ sel,
                        const float* __restrict__ samp, float* __restrict__ thr)
{
    __shared__ unsigned buf[8192];
    __shared__ unsigned bins[4096];
    __shared__ unsigned part[256];
    __shared__ unsigned selll[4];
    __shared__ unsigned wred[4];
    const int t = threadIdx.x;
    if (blockIdx.x < 256) {
        // local scan0: per-bin sums from sharded hist0 (identical in every block; no serialization)
        unsigned s = 0;
        #pragma unroll
        for (int m = 0; m < 16; m++) {
            int bin = t * 16 + m;
            unsigned bs = 0;
            #pragma unroll
            for (int sh = 0; sh < 8; sh++) bs += hist0[bin * 8 + sh];
            bins[bin] = bs;
            s += bs;
        }
        part[t] = s;
        for (int m = t; m < 8192; m += 256) buf[m] = 0;
        __syncthreads();
        if (t == 0) {
            for (int tg = 0; tg < 2; tg++) {
                unsigned r = tg ? 131072u : 131071u;
                int c = 0;
                while (part[c] <= r) { r -= part[c]; c++; }
                int b = c * 16;
                while (bins[b] <= r) { r -= bins[b]; b++; }
                selll[2 * tg] = (unsigned)b; selll[2 * tg + 1] = r;
            }
            if (blockIdx.x == 0) {
                sel[0] = selll[0]; sel[1] = selll[1]; sel[2] = selll[2]; sel[3] = selll[3];
            }
        }
        __syncthreads();
        unsigned p0 = selll[0], p1 = selll[2];
        const int e0 = blockIdx.x * 1024;
        for (int m = 0; m < 4; m++) {
            unsigned key = __float_as_uint(D2w[e0 + m * 256 + t]);
            if ((key >> 20) == p0) atomicAdd(&buf[(key >> 8) & 0xFFFu], 1u);
            if ((key >> 20) == p1) atomicAdd(&buf[4096 + ((key >> 8) & 0xFFFu)], 1u);
        }
        __syncthreads();
        for (int m = t; m < 8192; m += 256) { unsigned v = buf[m]; if (v) atomicAdd(&hist12[m], v); }
    } else {
        const int q = blockIdx.x - 256;
        // keys register-resident: 32 per thread, statically indexed
        unsigned kreg[32];
        #pragma unroll
        for (int i = 0; i < 32; i++) kreg[i] = fkey(samp[q * NS + i * 256 + t]);
        unsigned v = 0;
        for (int bit = 31; bit >= 0; bit--) {
            unsigned trial = v | (1u << bit);
            unsigned c = 0;
            #pragma unroll
            for (int i = 0; i < 32; i++) c += (kreg[i] < trial) ? 1u : 0u;
            #pragma unroll
            for (int off = 32; off > 0; off >>= 1) c += __shfl_down(c, off);
            if ((t & 63) == 0) wred[t >> 6] = c;
            __syncthreads();
            unsigned total = wred[0] + wred[1] + wred[2] + wred[3];
            __syncthreads();
            if (total <= (unsigned)(KNN - 1)) v = trial;
        }
        if (t == 0) {
            unsigned orig = (v & 0x80000000u) ? (v ^ 0x80000000u) : ~v;
            thr[q] = __uint_as_float(orig) + SLACK;
        }
    }
}

// filter tile body over a statically-named LDS buffer (keeps alias analysis exact so
// prefetch into the OTHER buffer overlaps with these ds_reads); also records approx score key
#define FILT_BODY(SBUF)                                                              \
    do {                                                                             \
        _Pragma("unroll")                                                            \
        for (int tt = 0; tt < 2; tt++) {                                             \
            const int r = (ck * 2 + tt) * 16 + lr;                                   \
            float xnv = xn[r];                                                       \
            bf16x8 bv[4];                                                            \
            _Pragma("unroll")                                                        \
            for (int ks2 = 0; ks2 < 4; ks2++)                                        \
                bv[ks2] = *(const bf16x8*)(SBUF + tt * 2048 + ks2 * 512 + lane * 8); \
            f32x4 acc4[4];                                                           \
            _Pragma("unroll")                                                        \
            for (int i = 0; i < 4; i++) acc4[i] = (f32x4){0.f, 0.f, 0.f, 0.f};       \
            _Pragma("unroll")                                                        \
            for (int ks2 = 0; ks2 < 4; ks2++)                                        \
                _Pragma("unroll")                                                    \
                for (int i = 0; i < 4; i++)                                          \
                    acc4[i] = __builtin_amdgcn_mfma_f32_16x16x32_bf16(a[i][ks2], bv[ks2], acc4[i], 0, 0, 0); \
            _Pragma("unroll")                                                        \
            for (int i = 0; i < 4; i++)                                              \
                _Pragma("unroll")                                                    \
                for (int reg = 0; reg < 4; reg++) {                                  \
                    float s = xnv - 2.f * acc4[i][reg];                              \
                    if (s <= th_r[i][reg]) {                                         \
                        unsigned qq = (unsigned)(w * 64 + i * 16 + quad * 4 + reg);  \
                        unsigned p = atomicAdd(&lcnt, 1u);                           \
                        if (p < 1024u) { lbuf[p] = (qq << 18) | (unsigned)r; lsco[p] = fkey(s); } \
                        else {                                                       \
                            unsigned dd2 = gbase + p;                                \
                            if (dd2 < EB) { eb[dd2] = (qq << 18) | (unsigned)r; ebs[dd2] = fkey(s); } \
                        }                                                            \
                    }                                                                \
                }                                                                    \
        }                                                                            \
    } while (0)

// ---- filt2: mf1-filter -> per-block lists (blocks 0..1023) | hist pass2 compact (1024..1279) ----
__global__ __launch_bounds__(256) void k_filt2(const unsigned short* __restrict__ tqsw,
    const unsigned short* __restrict__ xbf, const float* __restrict__ xn,
    const float* __restrict__ thr, unsigned* __restrict__ ebuf, unsigned* __restrict__ esco,
    unsigned* __restrict__ bcnt, const float* __restrict__ D2w,
    unsigned* __restrict__ hist12, unsigned* __restrict__ sel)
{
    if (blockIdx.x >= 1024) {
        // hist pass2 (compact 2KB LDS) + scan1; block 1024 persists sel[4..7]
        __shared__ unsigned h2c[512];
        __shared__ unsigned part2[256];
        __shared__ unsigned pfx[2];
        __shared__ unsigned rr[2];
        const int t = threadIdx.x;
        for (int tg = 0; tg < 2; tg++) {
            const unsigned* hh = hist12 + tg * 4096;
            unsigned s = 0;
            for (int m = 0; m < 16; m++) s += hh[t * 16 + m];
            part2[t] = s;
            __syncthreads();
            if (t == 0) {
                unsigned r = sel[1 + 2 * tg];
                int c = 0;
                while (part2[c] <= r) { r -= part2[c]; c++; }
                int b = c * 16;
                while (hh[b] <= r) { r -= hh[b]; b++; }
                pfx[tg] = (sel[2 * tg] << 12) | (unsigned)b;
                rr[tg] = r;
            }
            __syncthreads();
        }
        if (blockIdx.x == 1024 && t == 0) {
            sel[4] = pfx[0]; sel[5] = rr[0]; sel[6] = pfx[1]; sel[7] = rr[1];
        }
        h2c[t] = 0; h2c[256 + t] = 0;
        __syncthreads();
        unsigned p0 = pfx[0], p1 = pfx[1];
        const int e0 = (blockIdx.x - 1024) * 1024;
        for (int m = 0; m < 4; m++) {
            unsigned key = __float_as_uint(D2w[e0 + m * 256 + t]);
            if ((key >> 8) == p0) atomicAdd(&h2c[key & 0xFFu], 1u);
            if ((key >> 8) == p1) atomicAdd(&h2c[256 + (key & 0xFFu)], 1u);
        }
        __syncthreads();
        unsigned* gp = hist12 + 8192;
        unsigned v0 = h2c[t], v1 = h2c[256 + t];
        if (v0) atomicAdd(&gp[t], v0);
        if (v1) atomicAdd(&gp[4096 + t], v1);
        return;
    }
    __shared__ unsigned short sbA[4096]; // statically-named double buffers (alias-exact)
    __shared__ unsigned short sbB[4096];
    __shared__ unsigned lbuf[1024];      // packed (qq<<18)|r candidates
    __shared__ unsigned lsco[1024];      // matching approx score keys
    __shared__ unsigned lcnt;
    __shared__ unsigned gbase;           // running write offset into this block's ebuf list
    const int t = threadIdx.x;
    const int w = t >> 6, lane = t & 63;
    const int lr = lane & 15, quad = lane >> 4;
    unsigned* eb  = ebuf + (unsigned)blockIdx.x * EB;
    unsigned* ebs = esco + (unsigned)blockIdx.x * EB;
    bf16x8 a[4][4];
    #pragma unroll
    for (int i = 0; i < 4; i++)
        #pragma unroll
        for (int ks = 0; ks < 4; ks++)
            a[i][ks] = *(const bf16x8*)(tqsw + (w * 4 + i) * 2048 + ks * 512 + lane * 8);
    float th_r[4][4];
    #pragma unroll
    for (int i = 0; i < 4; i++)
        #pragma unroll
        for (int reg = 0; reg < 4; reg++)
            th_r[i][reg] = thr[w * 64 + i * 16 + quad * 4 + reg];
    int ck = blockIdx.x;
    bool phaseA = true;
    if (t == 0) { lcnt = 0; gbase = 0; }
    stage8k(xbf + (long)ck * 4096, sbA, w, lane);
    __syncthreads();
    while (true) {
        const int ckn = ck + 1024;
        const bool has = ckn < 6250;
        if (phaseA) {
            if (has) stage8k(xbf + (long)ckn * 4096, sbB, w, lane);
            FILT_BODY(sbA);
        } else {
            if (has) stage8k(xbf + (long)ckn * 4096, sbA, w, lane);
            FILT_BODY(sbB);
        }
        __syncthreads(); // publishes lcnt/lbuf; drains prefetch into the other buffer
        unsigned n = lcnt;
        if (!has || n >= 512u) {
            unsigned nf = (n < 1024u) ? n : 1024u;
            unsigned gb = gbase;
            for (unsigned m = t; m < nf; m += 256) {
                unsigned d = gb + m;
                if (d < EB) { eb[d] = lbuf[m]; ebs[d] = lsco[m]; }
            }
            __syncthreads();
            if (t == 0) { gbase = gb + n; lcnt = 0; }
            __syncthreads();
        }
        if (!has) break;
        ck = ckn; phaseA = !phaseA;
    }
    if (t == 0) bcnt[blockIdx.x] = (gbase < EB) ? gbase : EB;
}

// ---- scatmmd: scatter lists (idx + approx key) -> per-query arrays (0..127) | mmd exp-sum (128..383) ----
__global__ __launch_bounds__(256) void k_scatmmd(const unsigned* __restrict__ ebuf,
    const unsigned* __restrict__ esco, const unsigned* __restrict__ bcnt,
    int* __restrict__ cand_i, unsigned* __restrict__ ksa, unsigned* __restrict__ cnt,
    const float* __restrict__ D2w, const unsigned* __restrict__ hist12,
    const unsigned* __restrict__ sel, float* __restrict__ acc)
{
    const int t = threadIdx.x;
    if (blockIdx.x >= 128) {
        __shared__ unsigned h2[512];
        __shared__ float gsh;
        __shared__ float part[12];
        const int w = t >> 6;
        h2[t] = hist12[8192 + t];
        h2[256 + t] = hist12[8192 + 4096 + t];
        __syncthreads();
        if (t == 0) {
            unsigned key[2];
            for (int tg = 0; tg < 2; tg++) {
                unsigned r = sel[5 + 2 * tg];
                const unsigned* hh = h2 + tg * 256;
                int b = 0;
                while (hh[b] <= r) { r -= hh[b]; b++; }
                key[tg] = (sel[4 + 2 * tg] << 8) | (unsigned)b;
            }
            float med = 0.5f * (__uint_as_float(key[0]) + __uint_as_float(key[1]));
            float ssq = 0.5f * med;
            if (ssq < 1e-6f) ssq = 1.0f;
            gsh = 1.0f / (ssq + 1e-8f);
        }
        __syncthreads();
        const float g = gsh;
        float s[3] = {0.f, 0.f, 0.f};
        const int e0 = (blockIdx.x - 128) * 1024;
        #pragma unroll
        for (int m = 0; m < 4; m++) {
            int e = e0 + m * 256 + t;
            int i = e >> 9, j = e & 511;
            float v = expf(-g * D2w[e]);
            int qd = (i < 256) ? ((j < 256) ? 0 : 2) : ((j < 256) ? 2 : 1);
            s[qd] += v;
        }
        #pragma unroll
        for (int c = 0; c < 3; c++) {
            float x = s[c];
            #pragma unroll
            for (int off = 32; off > 0; off >>= 1) x += __shfl_down(x, off);
            if ((t & 63) == 0) part[w * 3 + c] = x;
        }
        __syncthreads();
        if (t == 0)
            for (int c = 0; c < 3; c++)
                atomicAdd(&acc[2 + c], part[c] + part[3 + c] + part[6 + c] + part[9 + c]);
        return;
    }
    __shared__ unsigned hist[256];
    __shared__ unsigned startp[256];
    const int b0 = blockIdx.x * 8;   // 128 blocks x 8 lists = 1024 lists
    hist[t] = 0;
    __syncthreads();
    for (int b = b0; b < b0 + 8; b++) {
        unsigned n = bcnt[b];
        const unsigned* e = ebuf + (unsigned)b * EB;
        for (unsigned m = t; m < n; m += 256)
            atomicAdd(&hist[e[m] >> 18], 1u);
    }
    __syncthreads();
    unsigned c = hist[t];
    if (c) {
        unsigned base = atomicAdd(&cnt[t * 16], c);
        startp[t] = ((unsigned)t << 13) + base;
    }
    __syncthreads();
    for (int b = b0; b < b0 + 8; b++) {
        unsigned n = bcnt[b];
        const unsigned* e = ebuf + (unsigned)b * EB;
        const unsigned* e2 = esco + (unsigned)b * EB;
        for (unsigned m = t; m < n; m += 256) {
            unsigned ent = e[m];
            unsigned sk = e2[m];
            unsigned qq = ent >> 18;
            unsigned pos = atomicAdd(&startp[qq], 1u);
            if (pos < ((qq + 1u) << 13)) { cand_i[pos] = (int)(ent & 0x3FFFFu); ksa[pos] = sk; }
        }
    }
}

// ---- rp: histogram band prune (barrier-cheap) -> exact rescore of survivors ->
//      wave0 exact top-50 -> softmax -> union KL; last block assembles the output ----
__global__ __launch_bounds__(1024) void k_rp(const float* __restrict__ comb,
                        const float* __restrict__ X,
                        const int* __restrict__ cand_i, const unsigned* __restrict__ ksa,
                        const unsigned* __restrict__ cnt,
                        const int* __restrict__ pri,
                        const float* __restrict__ prw, const int* __restrict__ qix,
                        const float* __restrict__ xn,
                        float* __restrict__ acc, unsigned* __restrict__ sel,
                        const float* __restrict__ ancp, const float* __restrict__ wregp,
                        float* __restrict__ out)
{
    __shared__ unsigned ks[CAP];     // approx keys (fallback path: overwritten by exact keys)
    __shared__ unsigned hs[4096];    // 12-bit histogram; later aliased: sidx=hs[0..2047], eks=hs[2048..4095]
    __shared__ unsigned wsum[16];
    __shared__ float qrow[D];
    __shared__ unsigned scnt, wpos, eqn, bsel, vsh;
    __shared__ int eq[64];
    __shared__ int pidx[KNN];
    __shared__ float l2s[KNN];
    __shared__ float pw[KNN];
    __shared__ int ci[100];
    __shared__ float pwv[50], qwv[50];
    __shared__ float pterm[100], qterm[100], kterm[100];
    __shared__ float Sp, Sq;
    const int q = blockIdx.x, t = threadIdx.x;
    if (t < D) qrow[t] = comb[q * D + t];
    if (t == 0) { wpos = 0; eqn = 0; scnt = 0; bsel = 4095u; }
    unsigned nn = cnt[q * 16];
    const int n = (nn < (unsigned)CAP) ? (int)nn : CAP;
    for (int m = t; m < 4096; m += 1024) hs[m] = 0;
    __syncthreads();
    // ---- load approx keys + build 12-bit histogram in one pass ----
    for (int m = t; m < n; m += 1024) {
        unsigned kv = ksa[q * CAP + m];
        ks[m] = kv;
        atomicAdd(&hs[kv >> 20], 1u);
    }
    __syncthreads();
    // ---- parallel bin-locate of approx kth (4 bins/thread, wave scan + cross-wave combine) ----
    int kk = KNN - 1; if (kk > n - 1) kk = n - 1;
    {
        unsigned h0 = hs[t * 4], h1 = hs[t * 4 + 1], h2 = hs[t * 4 + 2], h3 = hs[t * 4 + 3];
        unsigned c4 = h0 + h1 + h2 + h3;
        unsigned sc = c4;
        #pragma unroll
        for (int off = 1; off < 64; off <<= 1) {
            unsigned o = __shfl_up(sc, off);
            if ((t & 63) >= off) sc += o;
        }
        if ((t & 63) == 63) wsum[t >> 6] = sc;
        __syncthreads();
        unsigned wbase = 0;
        #pragma unroll
        for (int i = 0; i < 16; i++) wbase += (i < (t >> 6)) ? wsum[i] : 0u;
        unsigned excl = wbase + sc - c4;
        unsigned kku = (unsigned)kk;
        if (c4 > 0 && kku >= excl && kku < excl + c4) {
            unsigned cum = excl;
            int b = t * 4;
            if (kku >= cum + h0) { cum += h0; b++;
                if (kku >= cum + h1) { cum += h1; b++;
                    if (kku >= cum + h2) { cum += h2; b++; } } }
            bsel = (unsigned)b;
        }
    }
    __syncthreads();
    unsigned vkeep;
    {
        unsigned b = bsel;
        if (b >= 4095u) vkeep = 0xFFFFFFFFu;
        else {
            unsigned bk = (b + 1u) << 20;   // first key of next bin (>= all keys in bins <= b)
            unsigned bf = (bk & 0x80000000u) ? (bk ^ 0x80000000u) : ~bk;
            vkeep = fkey(__uint_as_float(bf) + BAND);
        }
    }
    // ---- survivor band scan (hist region dead -> alias as sidx/eks) ----
    int* sidx = (int*)hs;            // 2048 ints
    unsigned* eks = hs + 2048;       // 2048 keys
    for (int m = t; m < n; m += 1024) {
        if (ks[m] <= vkeep) {
            unsigned p = atomicAdd(&scnt, 1u);
            if (p < 2048u) sidx[p] = cand_i[q * CAP + m];
        }
    }
    __syncthreads();
    const bool cpath = (scnt <= 2048u);       // block-uniform
    const int ns = cpath ? (int)scnt : n;
    // ---- exact f32 rescore (survivors only, or all on overflow fallback) ----
    const int g = t >> 3, j = t & 7;          // 128 groups of 8 lanes
    if (cpath) {
        for (int m = g; m < ns; m += 128) {
            int r = sidx[m];
            const float4* xr = (const float4*)(X + (long)r * D);
            float s = 0.f;
            #pragma unroll
            for (int p = 0; p < 4; p++) {
                float4 xv = xr[j * 4 + p];
                float4 qv = *(const float4*)&qrow[(j * 4 + p) * 4];
                s = fmaf(xv.x, qv.x, fmaf(xv.y, qv.y, fmaf(xv.z, qv.z, fmaf(xv.w, qv.w, s))));
            }
            s += __shfl_down(s, 4); s += __shfl_down(s, 2); s += __shfl_down(s, 1);
            if (j == 0) eks[m] = fkey(xn[r] - 2.f * s);
        }
    } else {
        for (int m = g; m < ns; m += 128) {
            int r = cand_i[q * CAP + m];
            const float4* xr = (const float4*)(X + (long)r * D);
            float s = 0.f;
            #pragma unroll
            for (int p = 0; p < 4; p++) {
                float4 xv = xr[j * 4 + p];
                float4 qv = *(const float4*)&qrow[(j * 4 + p) * 4];
                s = fmaf(xv.x, qv.x, fmaf(xv.y, qv.y, fmaf(xv.z, qv.z, fmaf(xv.w, qv.w, s))));
            }
            s += __shfl_down(s, 4); s += __shfl_down(s, 2); s += __shfl_down(s, 1);
            if (j == 0) ks[m] = fkey(xn[r] - 2.f * s);   // overwrite approx keys
        }
    }
    __syncthreads();
    // ---- exact kth among ns keys: wave 0 only, shuffle-butterfly totals, NO block barriers ----
    int kk2 = KNN - 1; if (kk2 > ns - 1) kk2 = ns - 1;
    if (t < 64) {
        unsigned v = 0;
        for (int bit = 31; bit >= 0; bit--) {
            unsigned trial = v | (1u << bit);
            unsigned c = 0;
            for (int m = t; m < ns; m += 64) {
                unsigned kv2 = cpath ? eks[m] : ks[m];
                c += (kv2 < trial) ? 1u : 0u;
            }
            #pragma unroll
            for (int off = 32; off > 0; off >>= 1) c += __shfl_xor(c, off);
            if (c <= (unsigned)kk2) v = trial;
        }
        if (t == 0) vsh = v;
    }
    __syncthreads();
    const unsigned v = vsh;
    for (int m = t; m < ns; m += 1024) {
        unsigned kv = cpath ? eks[m] : ks[m];
        int r = cpath ? sidx[m] : cand_i[q * CAP + m];
        if (kv < v) {
            unsigned p = atomicAdd(&wpos, 1u);
            pidx[p] = r;
        } else if (kv == v) {
            unsigned p = atomicAdd(&eqn, 1u);
            if (p < 64) eq[p] = r;
        }
    }
    __syncthreads();
    if (t == 0) {
        int c1 = (int)wpos, need = KNN - c1;
        int ne = (eqn < 64u) ? (int)eqn : 64;
        for (int a = 0; a < ne; a++)
            for (int b2 = a + 1; b2 < ne; b2++)
                if (eq[b2] < eq[a]) { int tmp = eq[a]; eq[a] = eq[b2]; eq[b2] = tmp; }
        for (int a = 0; a < need && a < ne; a++) pidx[c1 + a] = eq[a];
    }
    __syncthreads();
    for (int nb = g; nb < KNN; nb += 128) {
        long r = pidx[nb];
        const float4* xr = (const float4*)(X + r * D);
        float s = 0.f;
        #pragma unroll
        for (int p = 0; p < 4; p++) {
            float4 xv = xr[j * 4 + p];
            float4 qv = *(const float4*)&qrow[(j * 4 + p) * 4];
            float d0 = qv.x - xv.x, d1 = qv.y - xv.y, d2 = qv.z - xv.z, d3 = qv.w - xv.w;
            s += d0 * d0 + d1 * d1 + d2 * d2 + d3 * d3;
        }
        s += __shfl_down(s, 4); s += __shfl_down(s, 2); s += __shfl_down(s, 1);
        if (j == 0) l2s[nb] = s;
    }
    int qi = qix[q];
    if (t >= 128 && t < 178) { int k = t - 128; ci[k] = pri[qi * 50 + k]; pwv[k] = prw[qi * 50 + k]; }
    __syncthreads();
    if (t < 64) {
        float logit = (t < KNN) ? (-l2s[t] * 10.0f) : -3.4e38f; // 1/tau = 10
        float m = logit;
        #pragma unroll
        for (int off = 32; off > 0; off >>= 1) m = fmaxf(m, __shfl_down(m, off));
        m = __shfl(m, 0);
        float e = (t < KNN) ? expf(logit - m) : 0.f;
        float ss = e;
        #pragma unroll
        for (int off = 32; off > 0; off >>= 1) ss += __shfl_down(ss, off);
        ss = __shfl(ss, 0);
        if (t < KNN) pw[t] = e / ss;
    }
    __syncthreads();
    if (t < 50) { ci[50 + t] = pidx[t]; qwv[t] = pw[t]; }
    __syncthreads();
    float pc = 0.f, qc = 0.f, mult = 0.f;
    if (t < 100) {
        int c = ci[t];
        float pr = 0.f, qr = 0.f;
        for (int k = 0; k < 50; k++) {
            bool m1 = (c == ci[k]); bool m2 = (c == ci[50 + k]);
            mult += (m1 ? 1.f : 0.f) + (m2 ? 1.f : 0.f);
            pr += m1 ? pwv[k] : 0.f;
            qr += m2 ? qwv[k] : 0.f;
        }
        pc = fmaxf(pr, 1e-8f); qc = fmaxf(qr, 1e-8f);
        pterm[t] = pc / mult; qterm[t] = qc / mult;
    }
    __syncthreads();
    if (t == 0) { float a = 0.f, b2 = 0.f; for (int m = 0; m < 100; m++) { a += pterm[m]; b2 += qterm[m]; } Sp = a; Sq = b2; }
    __syncthreads();
    if (t < 100) {
        float p = pc / Sp, qq2 = qc / Sq;
        kterm[t] = (p * (logf(p) - logf(qq2))) / mult;
    }
    __syncthreads();
    if (t == 0) {
        float s = 0.f;
        for (int m = 0; m < 100; m++) s += kterm[m];
        atomicAdd(&acc[1], s);
        __threadfence();                              // release this block's contribution
        unsigned old = atomicAdd(&sel[15], 1u);       // device-scope arrival counter
        if (old == 255u) {                            // last block assembles the output
            __threadfence();                          // acquire all blocks' contributions
            float lknn = atomicAdd(&acc[1], 0.f) / 256.f;
            float reg = 0.f;
            #pragma unroll
            for (int m = 0; m < 4; m++) reg += wregp[m];
            reg *= 0.5f;
            float anc = 0.f;
            for (int m = 0; m < 256; m++) anc += ancp[m];
            float lanc = anc / 256.f;
            float kxx = acc[2] / 65536.f, kyy = acc[3] / 65536.f, kxy = acc[4] / 131072.f;
            float ld = fmaxf(kxx + kyy - 2.f * kxy, 0.f);
            out[0] = ld + lknn + 1e-4f * reg + lanc;
            out[1] = ld; out[2] = lknn; out[3] = lanc;
        }
    }
}

extern "C" void kernel_launch(void* const* d_in, const int* in_sizes, int n_in,
                              void* d_out, int out_size, void* d_ws, size_t ws_size,
                              hipStream_t stream)
{
    (void)in_sizes; (void)n_in; (void)out_size; (void)ws_size;
    const float* q   = (const float*)d_in[0];
    const float* X   = (const float*)d_in[1];
    const float* W   = (const float*)d_in[2];
    const float* bb  = (const float*)d_in[3];
    const float* prw = (const float*)d_in[4];
    const int*   pri = (const int*)d_in[5];
    const int*   qix = (const int*)d_in[6];
    const int*   idx = (const int*)d_in[7];
    float* out = (float*)d_out;
    char* ws = (char*)d_ws;
    float*    acc   = (float*)(ws + OFF_ACC);
    unsigned* sel   = (unsigned*)(ws + OFF_SEL);
    unsigned* cnt   = (unsigned*)(ws + OFF_CNT);
    unsigned* hist0 = (unsigned*)(ws + OFF_HIST0);
    unsigned* hist12= (unsigned*)(ws + OFF_HIST12);
    float*    comb  = (float*)(ws + OFF_COMB);
    float*    D2w   = (float*)(ws + OFF_D2);
    float*    xn    = (float*)(ws + OFF_XN);
    float*    samp  = (float*)(ws + OFF_SAMP);
    float*    thr   = (float*)(ws + OFF_THR);
    int*      cix   = (int*)(ws + OFF_CANDI);
    unsigned* ebuf  = (unsigned*)(ws + OFF_EBUF);   // aliases samp (dead after k_h1thr)
    unsigned* esco  = (unsigned*)(ws + OFF_SCO);
    unsigned* bcnt  = (unsigned*)(ws + OFF_BCNT);
    unsigned* ksa   = (unsigned*)(ws + OFF_KSA);
    unsigned short* tqsw = (unsigned short*)(ws + OFF_TQSW);
    unsigned short* xbf  = (unsigned short*)(ws + OFF_XBF);
    float*    ancp  = (float*)(ws + OFF_ANCP);
    float*    wregp = (float*)(ws + OFF_WREGP);

    hipLaunchKernelGGL(k_phase1,  dim3(12764),   dim3(256), 0, stream, q, X, W, bb, idx, comb, tqsw, xbf, xn, ancp, wregp, acc);
    hipLaunchKernelGGL(k_d2m,     dim3(1280),    dim3(256), 0, stream, comb, D2w, hist0, tqsw, xbf, xn, samp);
    hipLaunchKernelGGL(k_h1thr,   dim3(512),     dim3(256), 0, stream, D2w, hist12, hist0, sel, samp, thr);
    hipLaunchKernelGGL(k_filt2,   dim3(1280),    dim3(256), 0, stream, tqsw, xbf, xn, thr, ebuf, esco, bcnt, D2w, hist12, sel);
    hipLaunchKernelGGL(k_scatmmd, dim3(384),     dim3(256), 0, stream, ebuf, esco, bcnt, cix, ksa, cnt, D2w, hist12, sel, acc);
    hipLaunchKernelGGL(k_rp,      dim3(256),     dim3(1024), 0, stream, comb, X, cix, ksa, cnt, pri, prw, qix, xn, acc, sel, ancp, wregp, out);
}